// Round 3
// baseline (420.799 us; speedup 1.0000x reference)
//
#include <hip/hip_runtime.h>

// Problem: B=16, N=128, F=64, K=128, C=3 (all fp32)
//   pa = S @ w[:F]  (+ b)     -> (B*N, K)
//   pb = S @ w[F:]            -> (B*N, K)
//   out[b,i,j,c,k] = (pa[b,i,k] + pb[b,j,k]) * dist[b,i,j,c]
// out = 402.65 MB fp32 -> HBM-write-bound.
//
// History: per-block-contiguous output slabs (192 KB/block) ran at ~2.7 TB/s
// effective store BW regardless of read path (L2 loads, LDS staging, NT/plain).
// The harness's own fill hits 6.2 TB/s with a grid-stride linear front.
// Theory: ~1024 concurrent scattered write streams thrash DRAM row buffers.
// This version grid-strides the OUTPUT linearly: each iteration the whole grid
// writes one contiguous 12 MB front, marching like the fill does.

#define BN   2048      // B*N rows
#define FF   64        // F
#define KK   128       // K

typedef float f4 __attribute__((ext_vector_type(4)));

// Kernel A: per-row mini-GEMM. One block per row r (b*N+i), 128 threads = one k each.
// pa gets bias folded in. W columns (stride-128) are coalesced across k-threads;
// W (64 KB) is L2-resident after first block. (~5 us, verified.)
__global__ __launch_bounds__(128) void proj_kernel(
    const float* __restrict__ S,   // (BN, F)
    const float* __restrict__ W,   // (2F, K)
    const float* __restrict__ bias,// (K,)
    float* __restrict__ pa,        // (BN, K)  = S@W[:F] + bias
    float* __restrict__ pb)        // (BN, K)  = S@W[F:]
{
    __shared__ float s[FF];
    const int r = blockIdx.x;
    const int k = threadIdx.x;
    if (k < FF) s[k] = S[r * FF + k];
    __syncthreads();

    float acc_a = bias[k];
    float acc_b = 0.0f;
#pragma unroll
    for (int f = 0; f < FF; ++f) {
        const float sv = s[f];                 // LDS broadcast, conflict-free
        acc_a = fmaf(sv, W[f * KK + k], acc_a);
        acc_b = fmaf(sv, W[(f + FF) * KK + k], acc_b);
    }
    pa[r * KK + k] = acc_a;
    pb[r * KK + k] = acc_b;
}

// Kernel B: expansion with a fill-like linear marching store front.
// G=2048 blocks x T=384 threads, 32 iterations.
// Global float4 index: F = it*786432 + g*384 + t  (12 MB contiguous per it).
// Since G*T = 64 * 12288 (64 output rows per front):
//   bi = it*64 + (g>>5)                    (row; advances 64/iter)
//   f  = (g&31)*384 + t                    (float4 offset within row; INVARIANT)
//   j  = f/96, c = (f%96)>>5, kq = f&31    (all loop-invariant)
//   b  = bi>>7 = it>>1                     (advances every 2 iters -> unroll 2)
// Reads (pa 1MB, pb 1MB, dist 3MB) are L2/L3-resident, affine-pointer loads.
// Stores are non-temporal so the 402 MB stream doesn't evict the read set.
__global__ __launch_bounds__(384) void expand_kernel(
    const float* __restrict__ dist,  // (B, N, N, C)
    const float* __restrict__ pa,    // (BN, K) incl. bias
    const float* __restrict__ pb,    // (BN, K)
    float* __restrict__ out)         // (B, N, N, C, K)
{
    const int g = blockIdx.x;
    const int t = threadIdx.x;          // 0..383

    const int q  = g >> 5;              // bi base 0..63
    const int f  = (g & 31) * 384 + t;  // 0..12287, loop-invariant
    const int j  = f / 96;              // 0..127
    const int r  = f - j * 96;          // 0..95
    const int c  = r >> 5;              // 0..2
    const int kq = r & 31;              // 0..31

    const f4*    __restrict__ pa_p   = (const f4*)pa + (size_t)q * 32 + kq;          // +2048/iter
    const f4*    __restrict__ pb_p   = (const f4*)pb + (size_t)j * 32 + kq;          // b=0 at it=0; +4096/pair
    const float* __restrict__ dist_p = dist + (size_t)q * 384 + (size_t)j * 3 + c;   // +24576/iter
    f4*          __restrict__ out_p  = (f4*)out + (size_t)g * 384 + t;               // +786432/iter

    // 16 pairs of iterations; pb is shared within a pair (same b).
#pragma unroll 4
    for (int it2 = 0; it2 < 16; ++it2) {
        const f4    p0 = pa_p[0];
        const f4    p1 = pa_p[2048];
        const f4    qq = pb_p[0];
        const float d0 = dist_p[0];
        const float d1 = dist_p[24576];

        f4 o0, o1;
        o0.x = (p0.x + qq.x) * d0;  o1.x = (p1.x + qq.x) * d1;
        o0.y = (p0.y + qq.y) * d0;  o1.y = (p1.y + qq.y) * d1;
        o0.z = (p0.z + qq.z) * d0;  o1.z = (p1.z + qq.z) * d1;
        o0.w = (p0.w + qq.w) * d0;  o1.w = (p1.w + qq.w) * d1;

        __builtin_nontemporal_store(o0, out_p);
        __builtin_nontemporal_store(o1, out_p + 786432);

        pa_p   += 4096;      // 2 rows of 64 -> 2*64*32 float4
        pb_p   += 4096;      // b += 1       -> 128*32 float4
        dist_p += 49152;     // 2*64*384 floats
        out_p  += 1572864;   // 2*12 MB fronts
    }
}

extern "C" void kernel_launch(void* const* d_in, const int* in_sizes, int n_in,
                              void* d_out, int out_size, void* d_ws, size_t ws_size,
                              hipStream_t stream) {
    const float* S    = (const float*)d_in[0];  // (16,128,64)
    const float* dist = (const float*)d_in[1];  // (16,128,128,3)
    const float* W    = (const float*)d_in[2];  // (128,128)
    const float* bias = (const float*)d_in[3];  // (128,)
    float* out = (float*)d_out;

    float* pa = (float*)d_ws;                   // BN*K floats = 1 MB
    float* pb = pa + (size_t)BN * KK;           // 1 MB

    proj_kernel<<<BN, 128, 0, stream>>>(S, W, bias, pa, pb);
    expand_kernel<<<BN, 384, 0, stream>>>(dist, pa, pb, out);
}